// Round 3
// baseline (319.171 us; speedup 1.0000x reference)
//
#include <hip/hip_runtime.h>
#include <hip/hip_bf16.h>
#include <math.h>

#define L 2048
#define D 256

typedef __attribute__((ext_vector_type(8))) short bf16x8;
typedef __attribute__((ext_vector_type(4))) float f32x4;
typedef __attribute__((ext_vector_type(4))) int i32x4;

__device__ __forceinline__ unsigned short f2bf(float f) {
    union { float f; unsigned int u; } v; v.f = f;
    unsigned int r = v.u + 0x7FFFu + ((v.u >> 16) & 1u);   // RNE
    return (unsigned short)(r >> 16);
}

// --- transpose Wv, Wo (f32 k-major) -> bf16 n-major ---------------------
__global__ __launch_bounds__(256) void wtrans_kernel(
    const float* __restrict__ Wv, const float* __restrict__ Wo,
    unsigned short* __restrict__ Wvt, unsigned short* __restrict__ Wot) {
    int idx = blockIdx.x * 256 + threadIdx.x;       // 0..131071
    int which = idx >> 16;
    int e = idx & 65535;
    int n = e >> 8, k = e & 255;
    const float* W = which ? Wo : Wv;
    unsigned short* Wt = which ? Wot : Wvt;
    Wt[n * 256 + k] = f2bf(W[k * 256 + n]);
}

// --- LDS-free GEMM: v = value @ Wv + bv, stored TRANSPOSED bf16 Vt[b][n][j]
__global__ __launch_bounds__(256) void gemm_v_kernel(
    const float* __restrict__ A,
    const unsigned short* __restrict__ Wt,   // [256][256] bf16 n-major
    const float* __restrict__ bias,
    unsigned short* __restrict__ Vt) {
    const int wave = threadIdx.x >> 6;
    const int lane = threadIdx.x & 63;
    const int mh = wave >> 1, nh = wave & 1;
    const int lm = lane & 15, q = lane >> 4;
    const int m0 = blockIdx.x * 64;
    const int n0 = blockIdx.y * 128;

    f32x4 acc[2][4];
#pragma unroll
    for (int i = 0; i < 2; i++)
#pragma unroll
        for (int j = 0; j < 4; j++) acc[i][j] = (f32x4)(0.f);

    int arow[2];
    arow[0] = m0 + mh * 32 + lm;
    arow[1] = arow[0] + 16;
    int ncol[4];
#pragma unroll
    for (int nf = 0; nf < 4; nf++) ncol[nf] = n0 + nh * 64 + nf * 16 + lm;

    for (int k0 = 0; k0 < 256; k0 += 32) {
        int kq = k0 + q * 8;
        bf16x8 bfr[4];
#pragma unroll
        for (int nf = 0; nf < 4; nf++)
            bfr[nf] = *reinterpret_cast<const bf16x8*>(Wt + ncol[nf] * 256 + kq);
        bf16x8 afr[2];
#pragma unroll
        for (int mf = 0; mf < 2; mf++) {
            const float* ap = A + arow[mf] * 256 + kq;
            f32x4 a0 = *reinterpret_cast<const f32x4*>(ap);
            f32x4 a1 = *reinterpret_cast<const f32x4*>(ap + 4);
            bf16x8 t;
#pragma unroll
            for (int e = 0; e < 4; e++) t[e] = (short)f2bf(a0[e]);
#pragma unroll
            for (int e = 0; e < 4; e++) t[4 + e] = (short)f2bf(a1[e]);
            afr[mf] = t;
        }
#pragma unroll
        for (int mf = 0; mf < 2; mf++)
#pragma unroll
            for (int nf = 0; nf < 4; nf++)
                acc[mf][nf] = __builtin_amdgcn_mfma_f32_16x16x32_bf16(
                    afr[mf], bfr[nf], acc[mf][nf], 0, 0, 0);
    }

#pragma unroll
    for (int mf = 0; mf < 2; mf++) {
        int mrow = m0 + mh * 32 + mf * 16 + q * 4;   // rows mrow..mrow+3
#pragma unroll
        for (int nf = 0; nf < 4; nf++) {
            int n = ncol[nf];
            float bias_n = bias[n];
            int b = mrow >> 11;
            int j = mrow & 2047;
            unsigned short* dst = Vt + (size_t)b * (D * L) + (size_t)n * L + j;
            ushort4 pk;
            pk.x = f2bf(acc[mf][nf][0] + bias_n);
            pk.y = f2bf(acc[mf][nf][1] + bias_n);
            pk.z = f2bf(acc[mf][nf][2] + bias_n);
            pk.w = f2bf(acc[mf][nf][3] + bias_n);
            *reinterpret_cast<ushort4*>(dst) = pk;
        }
    }
}

// --- BARRIER-FREE fused mask+exp+P@V -----------------------------------
// Wave = 16 rows x 128 V-cols x 512-j quarter. exp computed DIRECTLY in
// MFMA A-fragment layout (row=lane&15, k=(lane>>4)*8+j): no LDS, no sync.
// grid 1024 blocks x 4 waves: bid -> rt=bid>>1 (16-row tile), jh=bid&1;
// wave w: js = jh*2 + (w>>1), nh = w&1.
// part_acc[rt][js][nh][16][128] f32 ; part_l[rt][js][16]
__global__ __launch_bounds__(256) void attn_kernel(
    const float* __restrict__ atten, const float* __restrict__ mask,
    const int* __restrict__ pad, const unsigned short* __restrict__ Vt,
    float* __restrict__ part_acc, float* __restrict__ part_l) {
    const int bid = blockIdx.x;
    const int rt = bid >> 1;
    const int jh = bid & 1;
    const int wave = threadIdx.x >> 6;
    const int lane = threadIdx.x & 63;
    const int js = jh * 2 + (wave >> 1);
    const int nh = wave & 1;
    const int b  = rt >> 7;
    const int i0 = (rt & 127) << 4;
    const int lm = lane & 15, q = lane >> 4;

    const size_t rowbase = ((size_t)(b * L + i0 + lm)) * L + js * 512 + q * 8;
    const float* at = atten + rowbase;
    const float* mk = mask  + rowbase;
    const int*   pd = pad   + rowbase;
    const unsigned short* vb = Vt + (size_t)b * (D * L)
                             + (size_t)(nh * 128 + lm) * L + js * 512 + q * 8;

    f32x4 acc[8];
#pragma unroll
    for (int nf = 0; nf < 8; nf++) acc[nf] = (f32x4)(0.f);
    float l_th = 0.f;

    for (int jt = 0; jt < 8; jt++) {
        const int j0 = jt * 64;
        // Vt B-fragments (L2-resident), issued first
        bf16x8 bfr[2][8];
#pragma unroll
        for (int kk = 0; kk < 2; kk++)
#pragma unroll
            for (int nf = 0; nf < 8; nf++)
                bfr[kk][nf] = *reinterpret_cast<const bf16x8*>(
                    vb + (size_t)nf * (16 * L) + j0 + kk * 32);
        // logit streams for this lane's A-fragment rows/cols
        f32x4 a_[4], m_[4]; i32x4 p_[4];
#pragma unroll
        for (int kk = 0; kk < 2; kk++) {
            a_[kk * 2]     = *reinterpret_cast<const f32x4*>(at + j0 + kk * 32);
            a_[kk * 2 + 1] = *reinterpret_cast<const f32x4*>(at + j0 + kk * 32 + 4);
            m_[kk * 2]     = *reinterpret_cast<const f32x4*>(mk + j0 + kk * 32);
            m_[kk * 2 + 1] = *reinterpret_cast<const f32x4*>(mk + j0 + kk * 32 + 4);
            p_[kk * 2]     = *reinterpret_cast<const i32x4*>(pd + j0 + kk * 32);
            p_[kk * 2 + 1] = *reinterpret_cast<const i32x4*>(pd + j0 + kk * 32 + 4);
        }
        // exp + pack, directly into A-fragment registers
        bf16x8 afr[2];
#pragma unroll
        for (int kk = 0; kk < 2; kk++) {
            bf16x8 t;
#pragma unroll
            for (int h = 0; h < 2; h++)
#pragma unroll
                for (int e = 0; e < 4; e++) {
                    float pv = (m_[kk * 2 + h][e] < 0.5f || p_[kk * 2 + h][e] == 0)
                                   ? 0.f : __expf(a_[kk * 2 + h][e]);
                    l_th += pv;
                    t[h * 4 + e] = (short)f2bf(pv);
                }
            afr[kk] = t;
        }
        // P @ V
#pragma unroll
        for (int kk = 0; kk < 2; kk++)
#pragma unroll
            for (int nf = 0; nf < 8; nf++)
                acc[nf] = __builtin_amdgcn_mfma_f32_16x16x32_bf16(
                    afr[kk], bfr[kk][nf], acc[nf], 0, 0, 0);
    }

    // row-sum: reduce over the 4 q-lanes holding the same row lm
    l_th += __shfl_xor(l_th, 16);
    l_th += __shfl_xor(l_th, 32);

    float* pb = part_acc + ((size_t)(rt * 4 + js) * 2 + nh) * 2048;
#pragma unroll
    for (int nf = 0; nf < 8; nf++)
#pragma unroll
        for (int rg = 0; rg < 4; rg++)
            pb[(q * 4 + rg) * 128 + nf * 16 + lm] = acc[nf][rg];
    if (nh == 0 && lane < 16)
        part_l[(rt * 4 + js) * 16 + lm] = l_th;
}

// --- combine 4 j-partials, normalize, fused GEMM with Wo ----------------
// one block per 32 output rows (2 row-tiles)
__global__ __launch_bounds__(256) void combine_gemm_kernel(
    const float* __restrict__ part_acc, const float* __restrict__ part_l,
    const unsigned short* __restrict__ Wot, const float* __restrict__ bo,
    float* __restrict__ out) {
    const int rb = blockIdx.x;        // 0..255
    const int tid = threadIdx.x;
    const int wave = tid >> 6, lane = tid & 63;
    const int lm = lane & 15, q = lane >> 4;
    const int r = tid >> 3;           // 0..31 local row
    const int rt = rb * 2 + (r >> 4);
    const int rr = r & 15;
    const int cb = (tid & 7) * 32;    // 0..224
    const int nh = cb >> 7;
    const int cl = cb & 127;

    __shared__ __align__(16) unsigned short Alds[32][264];

    float l = 0.f;
#pragma unroll
    for (int js = 0; js < 4; js++) l += part_l[(rt * 4 + js) * 16 + rr];
    float inv = 1.f / l;
#pragma unroll
    for (int e = 0; e < 32; e += 4) {
        f32x4 s = (f32x4)(0.f);
#pragma unroll
        for (int js = 0; js < 4; js++)
            s += *reinterpret_cast<const f32x4*>(
                part_acc + ((size_t)(rt * 4 + js) * 2 + nh) * 2048 + rr * 128 + cl + e);
        s *= inv;
        ushort4 pk;
        pk.x = f2bf(s[0]); pk.y = f2bf(s[1]); pk.z = f2bf(s[2]); pk.w = f2bf(s[3]);
        *reinterpret_cast<ushort4*>(&Alds[r][cb + e]) = pk;
    }
    __syncthreads();

    // 32x256 @ 256x256 GEMM: A from LDS, B = Wot (n-major, global)
    f32x4 acc[2][4];
#pragma unroll
    for (int i = 0; i < 2; i++)
#pragma unroll
        for (int j = 0; j < 4; j++) acc[i][j] = (f32x4)(0.f);
    int ncol[4];
#pragma unroll
    for (int nf = 0; nf < 4; nf++) ncol[nf] = wave * 64 + nf * 16 + lm;

    for (int kk = 0; kk < 8; kk++) {
        int kq = kk * 32 + q * 8;
        bf16x8 bfr[4];
#pragma unroll
        for (int nf = 0; nf < 4; nf++)
            bfr[nf] = *reinterpret_cast<const bf16x8*>(Wot + ncol[nf] * 256 + kq);
#pragma unroll
        for (int mf = 0; mf < 2; mf++) {
            bf16x8 afr = *reinterpret_cast<const bf16x8*>(&Alds[mf * 16 + lm][kq]);
#pragma unroll
            for (int nf = 0; nf < 4; nf++)
                acc[mf][nf] = __builtin_amdgcn_mfma_f32_16x16x32_bf16(
                    afr, bfr[nf], acc[mf][nf], 0, 0, 0);
        }
    }

#pragma unroll
    for (int mf = 0; mf < 2; mf++) {
        int mrow = rb * 32 + mf * 16 + q * 4;
#pragma unroll
        for (int nf = 0; nf < 4; nf++) {
            int n = ncol[nf];
            float bn = bo[n];
#pragma unroll
            for (int rg = 0; rg < 4; rg++)
                out[(size_t)(mrow + rg) * 256 + n] = acc[mf][nf][rg] + bn;
        }
    }
}

extern "C" void kernel_launch(void* const* d_in, const int* in_sizes, int n_in,
                              void* d_out, int out_size, void* d_ws, size_t ws_size,
                              hipStream_t stream) {
    (void)in_sizes; (void)n_in; (void)out_size; (void)ws_size;
    const float* atten = (const float*)d_in[0];
    const float* value = (const float*)d_in[1];
    const float* mask  = (const float*)d_in[2];
    const int*   pad   = (const int*)d_in[3];
    const float* Wv    = (const float*)d_in[4];
    const float* bv    = (const float*)d_in[5];
    const float* Wo    = (const float*)d_in[6];
    const float* bo    = (const float*)d_in[7];
    float* out = (float*)d_out;

    char* ws = (char*)d_ws;
    unsigned short* Vt  = (unsigned short*)(ws);              // 4 MB  bf16 [B][D][L]
    unsigned short* Wvt = (unsigned short*)(ws + 4194304);    // 128 KB
    unsigned short* Wot = (unsigned short*)(ws + 4325376);    // 128 KB
    float* part_acc = (float*)(ws + 4456448);                 // 33.55 MB
    float* part_l   = (float*)(ws + 4456448 + 33554432);      // 128 KB

    wtrans_kernel<<<512, 256, 0, stream>>>(Wv, Wo, Wvt, Wot);
    gemm_v_kernel<<<dim3(128, 2), 256, 0, stream>>>(value, Wvt, bv, Vt);
    attn_kernel<<<1024, 256, 0, stream>>>(atten, mask, pad, Vt, part_acc, part_l);
    combine_gemm_kernel<<<256, 256, 0, stream>>>(part_acc, part_l, Wot, bo, out);
}

// Round 4
// 279.547 us; speedup vs baseline: 1.1417x; 1.1417x over previous
//
#include <hip/hip_runtime.h>
#include <hip/hip_bf16.h>
#include <math.h>

#define L 2048
#define D 256

typedef __attribute__((ext_vector_type(8))) short bf16x8;
typedef __attribute__((ext_vector_type(4))) float f32x4;
typedef __attribute__((ext_vector_type(4))) int i32x4;

__device__ __forceinline__ unsigned short f2bf(float f) {
    union { float f; unsigned int u; } v; v.f = f;
    unsigned int r = v.u + 0x7FFFu + ((v.u >> 16) & 1u);   // RNE
    return (unsigned short)(r >> 16);
}

// --- transpose Wv, Wo (f32 k-major) -> bf16 n-major ---------------------
__global__ __launch_bounds__(256) void wtrans_kernel(
    const float* __restrict__ Wv, const float* __restrict__ Wo,
    unsigned short* __restrict__ Wvt, unsigned short* __restrict__ Wot) {
    int idx = blockIdx.x * 256 + threadIdx.x;       // 0..131071
    int which = idx >> 16;
    int e = idx & 65535;
    int n = e >> 8, k = e & 255;
    const float* W = which ? Wo : Wv;
    unsigned short* Wt = which ? Wot : Wvt;
    Wt[n * 256 + k] = f2bf(W[k * 256 + n]);
}

// --- LDS-free GEMM: v = value @ Wv + bv, stored TRANSPOSED bf16 Vt[b][n][j]
__global__ __launch_bounds__(256) void gemm_v_kernel(
    const float* __restrict__ A,
    const unsigned short* __restrict__ Wt,   // [256][256] bf16 n-major
    const float* __restrict__ bias,
    unsigned short* __restrict__ Vt) {
    const int wave = threadIdx.x >> 6;
    const int lane = threadIdx.x & 63;
    const int mh = wave >> 1, nh = wave & 1;
    const int lm = lane & 15, q = lane >> 4;
    const int m0 = blockIdx.x * 64;
    const int n0 = blockIdx.y * 128;

    f32x4 acc[2][4];
#pragma unroll
    for (int i = 0; i < 2; i++)
#pragma unroll
        for (int j = 0; j < 4; j++) acc[i][j] = (f32x4)(0.f);

    int arow[2];
    arow[0] = m0 + mh * 32 + lm;
    arow[1] = arow[0] + 16;
    int ncol[4];
#pragma unroll
    for (int nf = 0; nf < 4; nf++) ncol[nf] = n0 + nh * 64 + nf * 16 + lm;

    for (int k0 = 0; k0 < 256; k0 += 32) {
        int kq = k0 + q * 8;
        bf16x8 bfr[4];
#pragma unroll
        for (int nf = 0; nf < 4; nf++)
            bfr[nf] = *reinterpret_cast<const bf16x8*>(Wt + ncol[nf] * 256 + kq);
        bf16x8 afr[2];
#pragma unroll
        for (int mf = 0; mf < 2; mf++) {
            const float* ap = A + arow[mf] * 256 + kq;
            f32x4 a0 = *reinterpret_cast<const f32x4*>(ap);
            f32x4 a1 = *reinterpret_cast<const f32x4*>(ap + 4);
            bf16x8 t;
#pragma unroll
            for (int e = 0; e < 4; e++) t[e] = (short)f2bf(a0[e]);
#pragma unroll
            for (int e = 0; e < 4; e++) t[4 + e] = (short)f2bf(a1[e]);
            afr[mf] = t;
        }
#pragma unroll
        for (int mf = 0; mf < 2; mf++)
#pragma unroll
            for (int nf = 0; nf < 4; nf++)
                acc[mf][nf] = __builtin_amdgcn_mfma_f32_16x16x32_bf16(
                    afr[mf], bfr[nf], acc[mf][nf], 0, 0, 0);
    }

#pragma unroll
    for (int mf = 0; mf < 2; mf++) {
        int mrow = m0 + mh * 32 + mf * 16 + q * 4;   // rows mrow..mrow+3
#pragma unroll
        for (int nf = 0; nf < 4; nf++) {
            int n = ncol[nf];
            float bias_n = bias[n];
            int b = mrow >> 11;
            int j = mrow & 2047;
            unsigned short* dst = Vt + (size_t)b * (D * L) + (size_t)n * L + j;
            ushort4 pk;
            pk.x = f2bf(acc[mf][nf][0] + bias_n);
            pk.y = f2bf(acc[mf][nf][1] + bias_n);
            pk.z = f2bf(acc[mf][nf][2] + bias_n);
            pk.w = f2bf(acc[mf][nf][3] + bias_n);
            *reinterpret_cast<ushort4*>(dst) = pk;
        }
    }
}

// --- PURE STREAMING: P = masked-exp(atten) bf16, l = row sums -----------
// One wave per row. Fully coalesced 1KB wave-loads, no LDS, no barriers.
// grid 2048 x 256: wave id = blockIdx*4 + wave -> row 0..8191.
__global__ __launch_bounds__(256) void p_kernel(
    const float* __restrict__ atten, const float* __restrict__ mask,
    const int* __restrict__ pad, unsigned short* __restrict__ P,
    float* __restrict__ lsum) {
    const int row = blockIdx.x * 4 + (threadIdx.x >> 6);   // 0..8191
    const int lane = threadIdx.x & 63;

    const float* at = atten + (size_t)row * L;
    const float* mk = mask  + (size_t)row * L;
    const int*   pd = pad   + (size_t)row * L;
    unsigned short* Pr = P + (size_t)row * L;

    float l_th = 0.f;
#pragma unroll
    for (int c = 0; c < 8; c++) {
        const int off = c * 256 + lane * 4;
        f32x4 a = *reinterpret_cast<const f32x4*>(at + off);
        f32x4 m = *reinterpret_cast<const f32x4*>(mk + off);
        i32x4 p = *reinterpret_cast<const i32x4*>(pd + off);
        ushort4 pk;
        float pv;
        pv = (m[0] < 0.5f || p[0] == 0) ? 0.f : __expf(a[0]); l_th += pv; pk.x = f2bf(pv);
        pv = (m[1] < 0.5f || p[1] == 0) ? 0.f : __expf(a[1]); l_th += pv; pk.y = f2bf(pv);
        pv = (m[2] < 0.5f || p[2] == 0) ? 0.f : __expf(a[2]); l_th += pv; pk.z = f2bf(pv);
        pv = (m[3] < 0.5f || p[3] == 0) ? 0.f : __expf(a[3]); l_th += pv; pk.w = f2bf(pv);
        *reinterpret_cast<ushort4*>(Pr + off) = pk;
    }
#pragma unroll
    for (int off = 1; off < 64; off <<= 1) l_th += __shfl_xor(l_th, off);
    if (lane == 0) lsum[row] = l_th;
}

// --- barrier-free GEMM  T = P @ Vt  (k=2048), normalize, fuse out-GEMM --
// Block = 32 rows x 256 n (4 waves; wave w: n in [w*64, w*64+64)).
// Both operands k-contiguous -> direct 16B global fragment loads, no LDS.
// Software-pipelined (next frags loaded before MFMAs), no barrier in k-loop.
__global__ __launch_bounds__(256) void pv_out_kernel(
    const unsigned short* __restrict__ P, const unsigned short* __restrict__ Vt,
    const float* __restrict__ lsum, const unsigned short* __restrict__ Wot,
    const float* __restrict__ bo, float* __restrict__ out) {
    const int rb = blockIdx.x;          // 0..255 -> rows rb*32..+31
    const int tid = threadIdx.x;
    const int w = tid >> 6, lane = tid & 63;
    const int lm = lane & 15, q = lane >> 4;
    const int b = rb >> 6;
    const int row0 = rb * 32;

    const unsigned short* pA = P + (size_t)row0 * L + q * 8;
    const unsigned short* pB = Vt + (size_t)b * (D * L) + (size_t)(w * 64) * L + q * 8;

    f32x4 acc[2][4];
#pragma unroll
    for (int i = 0; i < 2; i++)
#pragma unroll
        for (int j = 0; j < 4; j++) acc[i][j] = (f32x4)(0.f);

    bf16x8 Ac[2][2], Bc[2][4], An[2][2], Bn[2][4];
#pragma unroll
    for (int kk = 0; kk < 2; kk++) {
#pragma unroll
        for (int mf = 0; mf < 2; mf++)
            Ac[kk][mf] = *reinterpret_cast<const bf16x8*>(pA + (mf * 16 + lm) * L + kk * 32);
#pragma unroll
        for (int nf = 0; nf < 4; nf++)
            Bc[kk][nf] = *reinterpret_cast<const bf16x8*>(pB + (nf * 16 + lm) * L + kk * 32);
    }

    for (int k0 = 0; k0 < 2048; k0 += 64) {
        if (k0 + 64 < 2048) {
            const int kn = k0 + 64;
#pragma unroll
            for (int kk = 0; kk < 2; kk++) {
#pragma unroll
                for (int mf = 0; mf < 2; mf++)
                    An[kk][mf] = *reinterpret_cast<const bf16x8*>(
                        pA + (mf * 16 + lm) * L + kn + kk * 32);
#pragma unroll
                for (int nf = 0; nf < 4; nf++)
                    Bn[kk][nf] = *reinterpret_cast<const bf16x8*>(
                        pB + (nf * 16 + lm) * L + kn + kk * 32);
            }
        }
#pragma unroll
        for (int kk = 0; kk < 2; kk++)
#pragma unroll
            for (int mf = 0; mf < 2; mf++)
#pragma unroll
                for (int nf = 0; nf < 4; nf++)
                    acc[mf][nf] = __builtin_amdgcn_mfma_f32_16x16x32_bf16(
                        Ac[kk][mf], Bc[kk][nf], acc[mf][nf], 0, 0, 0);
#pragma unroll
        for (int kk = 0; kk < 2; kk++) {
#pragma unroll
            for (int mf = 0; mf < 2; mf++) Ac[kk][mf] = An[kk][mf];
#pragma unroll
            for (int nf = 0; nf < 4; nf++) Bc[kk][nf] = Bn[kk][nf];
        }
    }

    // normalize (÷l) and park T as bf16 in LDS (C-layout -> A-layout)
    __shared__ __align__(16) unsigned short Alds[32][264];
#pragma unroll
    for (int mf = 0; mf < 2; mf++) {
        float inv[4];
#pragma unroll
        for (int rg = 0; rg < 4; rg++)
            inv[rg] = 1.f / lsum[row0 + mf * 16 + q * 4 + rg];
#pragma unroll
        for (int nf = 0; nf < 4; nf++) {
            int col = w * 64 + nf * 16 + lm;
#pragma unroll
            for (int rg = 0; rg < 4; rg++)
                Alds[mf * 16 + q * 4 + rg][col] = f2bf(acc[mf][nf][rg] * inv[rg]);
        }
    }
    __syncthreads();

    // out = T @ Wo + bo   (32x256 @ 256x256, A from LDS, B = Wot global/L2)
    f32x4 oacc[2][4];
#pragma unroll
    for (int i = 0; i < 2; i++)
#pragma unroll
        for (int j = 0; j < 4; j++) oacc[i][j] = (f32x4)(0.f);
    int ncol[4];
#pragma unroll
    for (int nf = 0; nf < 4; nf++) ncol[nf] = w * 64 + nf * 16 + lm;

    for (int kk = 0; kk < 8; kk++) {
        int kq = kk * 32 + q * 8;
        bf16x8 bfr[4];
#pragma unroll
        for (int nf = 0; nf < 4; nf++)
            bfr[nf] = *reinterpret_cast<const bf16x8*>(Wot + ncol[nf] * 256 + kq);
#pragma unroll
        for (int mf = 0; mf < 2; mf++) {
            bf16x8 afr = *reinterpret_cast<const bf16x8*>(&Alds[mf * 16 + lm][kq]);
#pragma unroll
            for (int nf = 0; nf < 4; nf++)
                oacc[mf][nf] = __builtin_amdgcn_mfma_f32_16x16x32_bf16(
                    afr, bfr[nf], oacc[mf][nf], 0, 0, 0);
        }
    }

#pragma unroll
    for (int mf = 0; mf < 2; mf++) {
        int mrow = row0 + mf * 16 + q * 4;
#pragma unroll
        for (int nf = 0; nf < 4; nf++) {
            int n = ncol[nf];
            float bn = bo[n];
#pragma unroll
            for (int rg = 0; rg < 4; rg++)
                out[(size_t)(mrow + rg) * 256 + n] = oacc[mf][nf][rg] + bn;
        }
    }
}

extern "C" void kernel_launch(void* const* d_in, const int* in_sizes, int n_in,
                              void* d_out, int out_size, void* d_ws, size_t ws_size,
                              hipStream_t stream) {
    (void)in_sizes; (void)n_in; (void)out_size; (void)ws_size;
    const float* atten = (const float*)d_in[0];
    const float* value = (const float*)d_in[1];
    const float* mask  = (const float*)d_in[2];
    const int*   pad   = (const int*)d_in[3];
    const float* Wv    = (const float*)d_in[4];
    const float* bv    = (const float*)d_in[5];
    const float* Wo    = (const float*)d_in[6];
    const float* bo    = (const float*)d_in[7];
    float* out = (float*)d_out;

    char* ws = (char*)d_ws;
    unsigned short* Vt  = (unsigned short*)(ws);              // 4 MB  bf16 [B][D][L]
    unsigned short* Wvt = (unsigned short*)(ws + 4194304);    // 128 KB
    unsigned short* Wot = (unsigned short*)(ws + 4325376);    // 128 KB
    unsigned short* P   = (unsigned short*)(ws + 4456448);    // 33.55 MB bf16 [8192][2048]
    float* lsum         = (float*)(ws + 38010880);            // 32 KB

    wtrans_kernel<<<512, 256, 0, stream>>>(Wv, Wo, Wvt, Wot);
    gemm_v_kernel<<<dim3(128, 2), 256, 0, stream>>>(value, Wvt, bv, Vt);
    p_kernel<<<2048, 256, 0, stream>>>(atten, mask, pad, P, lsum);
    pv_out_kernel<<<256, 256, 0, stream>>>(P, Vt, lsum, Wot, bo, out);
}